// Round 2
// baseline (561.778 us; speedup 1.0000x reference)
//
#include <hip/hip_runtime.h>

// ---------------------------------------------------------------------------
// CrossAttentionBlockPatched: B=4, Lq=512, Lkv=2048, DIM=1024, H=16, hd=64,
// MLP_HIDDEN=4096, TAU=2.0, EPS=1e-6.
// Inputs/outputs fp32 (per reference dtypes); internal compute bf16 MFMA with
// fp32 accumulation.
// ---------------------------------------------------------------------------

typedef __attribute__((ext_vector_type(8))) short short8_t;   // 8 x bf16
typedef __attribute__((ext_vector_type(4))) float f32x4_t;    // 4 x fp32

__device__ __forceinline__ float b2f(short s) {
    union { float f; unsigned u; } c;
    c.u = ((unsigned)(unsigned short)s) << 16;
    return c.f;
}
__device__ __forceinline__ short f2b(float f) {
    union { float f; unsigned u; } c;
    c.f = f;
    unsigned u = c.u;
    unsigned r = (u + 0x7FFFu + ((u >> 16) & 1u)) >> 16;
    return (short)r;
}

// ---------------------------------------------------------------------------
// fp32 -> bf16 cast (vectorized float4 -> short4); n must be multiple of 4.
// ---------------------------------------------------------------------------
__global__ __launch_bounds__(256) void cast_kernel(
    const float* __restrict__ in, short* __restrict__ out, int n4)
{
    const int i = blockIdx.x * 256 + threadIdx.x;
    if (i < n4) {
        const float4 v = ((const float4*)in)[i];
        short4 o;
        o.x = f2b(v.x); o.y = f2b(v.y); o.z = f2b(v.z); o.w = f2b(v.w);
        ((short4*)out)[i] = o;
    }
}

// ---------------------------------------------------------------------------
// LayerNorm: one block (256 thr) per 1024-elem row. fp32 in, bf16 out.
// ---------------------------------------------------------------------------
__global__ __launch_bounds__(256) void ln_kernel(
    const float* __restrict__ x, const float* __restrict__ w,
    const float* __restrict__ bia, short* __restrict__ y)
{
    const int row = blockIdx.x, tid = threadIdx.x;
    const float4 t = *(const float4*)(x + (size_t)row * 1024 + tid * 4);
    float v[4] = {t.x, t.y, t.z, t.w};
    float s = v[0] + v[1] + v[2] + v[3];
    float s2 = v[0]*v[0] + v[1]*v[1] + v[2]*v[2] + v[3]*v[3];
    #pragma unroll
    for (int off = 1; off < 64; off <<= 1) {
        s  += __shfl_xor(s, off);
        s2 += __shfl_xor(s2, off);
    }
    __shared__ float red[8];
    const int wave = tid >> 6, lane = tid & 63;
    if (lane == 0) { red[wave] = s; red[4 + wave] = s2; }
    __syncthreads();
    s  = red[0] + red[1] + red[2] + red[3];
    s2 = red[4] + red[5] + red[6] + red[7];
    const float mu  = s * (1.0f / 1024.0f);
    const float var = s2 * (1.0f / 1024.0f) - mu * mu;
    const float rstd = rsqrtf(var + 1e-6f);
    const float4 wv = *(const float4*)(w + tid * 4);
    const float4 bv = *(const float4*)(bia + tid * 4);
    short4 o;
    o.x = f2b((v[0] - mu) * rstd * wv.x + bv.x);
    o.y = f2b((v[1] - mu) * rstd * wv.y + bv.y);
    o.z = f2b((v[2] - mu) * rstd * wv.z + bv.z);
    o.w = f2b((v[3] - mu) * rstd * wv.w + bv.w);
    *(short4*)(y + (size_t)row * 1024 + tid * 4) = o;
}

// ---------------------------------------------------------------------------
// L2 normalize rows of 64 bf16 elements, in place. One wave per row.
// ---------------------------------------------------------------------------
__global__ __launch_bounds__(256) void l2norm_kernel(short* __restrict__ x, int nrows)
{
    const int row = blockIdx.x * 4 + (threadIdx.x >> 6);
    const int lane = threadIdx.x & 63;
    if (row >= nrows) return;
    short* p = x + (size_t)row * 64 + lane;
    const float v = b2f(*p);
    float s = v * v;
    #pragma unroll
    for (int off = 1; off < 64; off <<= 1) s += __shfl_xor(s, off);
    const float n = sqrtf(s);
    const float sc = 1.0f / fmaxf(n, 1e-6f);
    *p = f2b(v * sc);
}

// ---------------------------------------------------------------------------
// V transpose: v[b][kv][h*64+d] -> vt[((b*16+h)*64+d)][kv]  (per b,h: [64][2048])
// ---------------------------------------------------------------------------
__global__ __launch_bounds__(256) void transpose_v_kernel(
    const short* __restrict__ v, short* __restrict__ vt)
{
    const int kvt = blockIdx.x, h = blockIdx.y, b = blockIdx.z;
    const int tid = threadIdx.x;
    __shared__ __attribute__((aligned(16))) short T[64][72];
    const int kv0 = kvt * 64;
    #pragma unroll
    for (int p = 0; p < 2; ++p) {
        const int idx = p * 256 + tid;
        const int row = idx >> 3, col = (idx & 7) * 8;
        *(int4*)&T[row][col] =
            *(const int4*)(v + (size_t)(b * 2048 + kv0 + row) * 1024 + h * 64 + col);
    }
    __syncthreads();
    #pragma unroll
    for (int p = 0; p < 2; ++p) {
        const int idx = p * 256 + tid;
        const int d = idx >> 3, c0 = (idx & 7) * 8;
        short tmp[8];
        #pragma unroll
        for (int j = 0; j < 8; ++j) tmp[j] = T[c0 + j][d];
        *(int4*)(vt + (size_t)((b * 16 + h) * 64 + d) * 2048 + kv0 + c0) = *(int4*)tmp;
    }
}

// ---------------------------------------------------------------------------
// GEMM: C[M,N] = epilogue(A[M,K] @ W[N,K]^T). A,W bf16. 128x128 tile, 256 thr
// (4 waves), each wave 64x64 via 4x4 mfma_f32_16x16x32_bf16 tiles. BK=32.
// EPI: 0 = plain bf16 store
//      1 = outF = resF + alpha*(acc + bias)            (attention out-proj)
//      2 = out16 = gelu_exact(acc + bias)              (fc1)
//      3 = outF = resF + alpha*(acc + bias)            (fc2 / final, fp32 out)
// bias/alpha/res fp32.
// ---------------------------------------------------------------------------
template <int EPI>
__global__ __launch_bounds__(256) void gemm_bt_kernel(
    const short* __restrict__ A, const short* __restrict__ W,
    int M, int N, int K,
    const float* __restrict__ bias,
    const float* __restrict__ resF,
    const float* __restrict__ alpha,
    short* __restrict__ out16,
    float* __restrict__ outF)
{
    __shared__ __attribute__((aligned(16))) short As[128][40];
    __shared__ __attribute__((aligned(16))) short Bs[128][40];
    const int bm = blockIdx.y * 128, bn = blockIdx.x * 128;
    const int tid = threadIdx.x;
    const int wave = tid >> 6, lane = tid & 63;
    const int wm = (wave >> 1) * 64, wn = (wave & 1) * 64;
    const int l15 = lane & 15, quad = lane >> 4;

    f32x4_t acc[4][4];
    #pragma unroll
    for (int mi = 0; mi < 4; ++mi)
        #pragma unroll
        for (int ni = 0; ni < 4; ++ni)
            acc[mi][ni] = (f32x4_t){0.f, 0.f, 0.f, 0.f};

    const int srow = tid >> 2;          // 0..63
    const int scol = (tid & 3) * 8;     // 0,8,16,24

    for (int k0 = 0; k0 < K; k0 += 32) {
        __syncthreads();
        #pragma unroll
        for (int p = 0; p < 2; ++p) {
            const int row = p * 64 + srow;
            *(int4*)&As[row][scol] =
                *(const int4*)(A + (size_t)(bm + row) * K + k0 + scol);
            *(int4*)&Bs[row][scol] =
                *(const int4*)(W + (size_t)(bn + row) * K + k0 + scol);
        }
        __syncthreads();
        short8_t af[4], bf[4];
        #pragma unroll
        for (int mi = 0; mi < 4; ++mi)
            af[mi] = *(const short8_t*)&As[wm + mi * 16 + l15][quad * 8];
        #pragma unroll
        for (int ni = 0; ni < 4; ++ni)
            bf[ni] = *(const short8_t*)&Bs[wn + ni * 16 + l15][quad * 8];
        #pragma unroll
        for (int mi = 0; mi < 4; ++mi)
            #pragma unroll
            for (int ni = 0; ni < 4; ++ni)
                acc[mi][ni] = __builtin_amdgcn_mfma_f32_16x16x32_bf16(
                    af[mi], bf[ni], acc[mi][ni], 0, 0, 0);
    }

    float a = 0.f;
    if (EPI == 1 || EPI == 3) a = alpha[0];

    #pragma unroll
    for (int mi = 0; mi < 4; ++mi) {
        #pragma unroll
        for (int ni = 0; ni < 4; ++ni) {
            const int n = bn + wn + ni * 16 + l15;
            float bb = 0.f;
            if (EPI != 0) bb = bias[n];
            #pragma unroll
            for (int r = 0; r < 4; ++r) {
                const int m = bm + wm + mi * 16 + quad * 4 + r;
                const size_t idx = (size_t)m * N + n;
                const float x = acc[mi][ni][r];
                if (EPI == 0) {
                    out16[idx] = f2b(x);
                } else if (EPI == 1) {
                    outF[idx] = resF[idx] + a * (x + bb);
                } else if (EPI == 2) {
                    const float t = x + bb;
                    out16[idx] = f2b(0.5f * t * (1.0f + erff(t * 0.70710678118f)));
                } else { // EPI == 3
                    outF[idx] = resF[idx] + a * (x + bb);
                }
            }
        }
    }
}

// ---------------------------------------------------------------------------
// Attention: per block = (q-tile of 64, head, batch); 4 waves, wave = 16 Q rows.
// S = (Q K^T)/tau, P = exp(S) (no running max needed: |q.k|<=1 after l2norm),
// running denominator l, O += P V. P goes C-layout -> LDS -> A-layout.
// q: [B,512,1024] bf16 (l2-normed), k: [B,2048,1024] bf16 (l2-normed),
// vt: [B,16,64,2048] bf16, ctx out: [B,512,1024] bf16.
// ---------------------------------------------------------------------------
__global__ __launch_bounds__(256) void attn_kernel(
    const short* __restrict__ q, const short* __restrict__ k,
    const short* __restrict__ vt, short* __restrict__ ctx)
{
    const int qt = blockIdx.x;   // 0..7
    const int h  = blockIdx.y;   // 0..15
    const int b  = blockIdx.z;   // 0..3
    const int tid = threadIdx.x;
    const int wave = tid >> 6, lane = tid & 63;
    const int l15 = lane & 15, quad = lane >> 4;
    const int q0 = qt * 64 + wave * 16;

    __shared__ __attribute__((aligned(16))) short P[4][16][72];

    const short* qbase = q + (size_t)(b * 512 + q0 + l15) * 1024 + h * 64 + quad * 8;
    const short8_t aq0 = *(const short8_t*)(qbase);
    const short8_t aq1 = *(const short8_t*)(qbase + 32);

    const short* kbase = k + (size_t)(b * 2048) * 1024 + h * 64 + quad * 8;
    const short* vbase = vt + (size_t)((b * 16 + h) * 64) * 2048;

    f32x4_t oacc[4];
    #pragma unroll
    for (int u = 0; u < 4; ++u) oacc[u] = (f32x4_t){0.f, 0.f, 0.f, 0.f};
    float l[4] = {0.f, 0.f, 0.f, 0.f};

    for (int t = 0; t < 32; ++t) {
        const int kv0 = t * 64;
        f32x4_t s[4];
        #pragma unroll
        for (int ss = 0; ss < 4; ++ss) {
            const short* kp = kbase + (size_t)(kv0 + ss * 16 + l15) * 1024;
            const short8_t bk0 = *(const short8_t*)(kp);
            const short8_t bk1 = *(const short8_t*)(kp + 32);
            f32x4_t acc = (f32x4_t){0.f, 0.f, 0.f, 0.f};
            acc = __builtin_amdgcn_mfma_f32_16x16x32_bf16(aq0, bk0, acc, 0, 0, 0);
            acc = __builtin_amdgcn_mfma_f32_16x16x32_bf16(aq1, bk1, acc, 0, 0, 0);
            s[ss] = acc;
        }
        float rs[4] = {0.f, 0.f, 0.f, 0.f};
        #pragma unroll
        for (int ss = 0; ss < 4; ++ss)
            #pragma unroll
            for (int r = 0; r < 4; ++r) {
                const float p = __expf(s[ss][r] * 0.5f);   // 1/TAU = 0.5
                s[ss][r] = p;
                rs[r] += p;
            }
        #pragma unroll
        for (int r = 0; r < 4; ++r) {
            float v = rs[r];
            v += __shfl_xor(v, 1);
            v += __shfl_xor(v, 2);
            v += __shfl_xor(v, 4);
            v += __shfl_xor(v, 8);
            l[r] += v;
        }
        // C-layout -> LDS (per-wave private region; same-wave ordering)
        #pragma unroll
        for (int ss = 0; ss < 4; ++ss)
            #pragma unroll
            for (int r = 0; r < 4; ++r)
                P[wave][quad * 4 + r][ss * 16 + l15] = f2b(s[ss][r]);
        // LDS -> A-layout fragments
        const short8_t ap0 = *(const short8_t*)&P[wave][l15][quad * 8];
        const short8_t ap1 = *(const short8_t*)&P[wave][l15][32 + quad * 8];
        #pragma unroll
        for (int u = 0; u < 4; ++u) {
            const short* vp = vbase + (size_t)(u * 16 + l15) * 2048 + kv0 + quad * 8;
            const short8_t bv0 = *(const short8_t*)(vp);
            const short8_t bv1 = *(const short8_t*)(vp + 32);
            oacc[u] = __builtin_amdgcn_mfma_f32_16x16x32_bf16(ap0, bv0, oacc[u], 0, 0, 0);
            oacc[u] = __builtin_amdgcn_mfma_f32_16x16x32_bf16(ap1, bv1, oacc[u], 0, 0, 0);
        }
    }
    #pragma unroll
    for (int u = 0; u < 4; ++u)
        #pragma unroll
        for (int r = 0; r < 4; ++r) {
            const float val = oacc[u][r] / l[r];
            ctx[(size_t)(b * 512 + q0 + quad * 4 + r) * 1024 + h * 64 + u * 16 + l15] =
                f2b(val);
        }
}

// ---------------------------------------------------------------------------
extern "C" void kernel_launch(void* const* d_in, const int* in_sizes, int n_in,
                              void* d_out, int out_size, void* d_ws, size_t ws_size,
                              hipStream_t stream)
{
    const float* q_tokens  = (const float*)d_in[0];
    const float* kv_tokens = (const float*)d_in[1];
    const float* q_ln_w    = (const float*)d_in[2];
    const float* q_ln_b    = (const float*)d_in[3];
    const float* kv_ln_w   = (const float*)d_in[4];
    const float* kv_ln_b   = (const float*)d_in[5];
    const float* mlp_ln_w  = (const float*)d_in[6];
    const float* mlp_ln_b  = (const float*)d_in[7];
    const float* Wq        = (const float*)d_in[8];
    const float* Wk        = (const float*)d_in[9];
    const float* Wv        = (const float*)d_in[10];
    const float* Wo        = (const float*)d_in[11];
    const float* bo        = (const float*)d_in[12];
    const float* fc1_w     = (const float*)d_in[13];
    const float* fc1_b     = (const float*)d_in[14];
    const float* fc2_w     = (const float*)d_in[15];
    const float* fc2_b     = (const float*)d_in[16];
    const float* alpha_attn = (const float*)d_in[17];
    const float* alpha_mlp  = (const float*)d_in[18];

    char* ws = (char*)d_ws;
    const size_t MB = (size_t)1 << 20;
    // Overlayed workspace layout (peak 96 MB):
    short* kvn  = (short*)(ws);              // 16 MB [8192,1024] bf16; dead after Wv gemm
    short* vtb  = (short*)(ws);              //       reuses kvn region: [4,16,64,2048]
    short* kbuf = (short*)(ws + 16 * MB);    // 16 MB [8192,1024]
    short* vbuf = (short*)(ws + 32 * MB);    // 16 MB [8192,1024]; dead after transpose
    short* h1   = (short*)(ws + 32 * MB);    //       reuses vbuf region: [2048,4096]
    short* qn   = (short*)(ws + 48 * MB);    //  4 MB [2048,1024]
    short* qbuf = (short*)(ws + 52 * MB);    //  4 MB [2048,1024]
    short* ctx  = (short*)(ws + 56 * MB);    //  4 MB [2048,1024]
    float* aout = (float*)(ws + 60 * MB);    //  8 MB [2048,1024] fp32
    short* hn   = (short*)(ws + 68 * MB);    //  4 MB [2048,1024]
    short* Wq_b  = (short*)(ws + 72 * MB);   //  2 MB each
    short* Wk_b  = (short*)(ws + 74 * MB);
    short* Wv_b  = (short*)(ws + 76 * MB);
    short* Wo_b  = (short*)(ws + 78 * MB);
    short* fc1_wb = (short*)(ws + 80 * MB);  //  8 MB
    short* fc2_wb = (short*)(ws + 88 * MB);  //  8 MB

    // 0) Cast weights fp32 -> bf16 (1M elems each for W*, 4M for fc*)
    const int n4_1m = (1024 * 1024) / 4, n4_4m = (4096 * 1024) / 4;
    cast_kernel<<<(n4_1m + 255) / 256, 256, 0, stream>>>(Wq, Wq_b, n4_1m);
    cast_kernel<<<(n4_1m + 255) / 256, 256, 0, stream>>>(Wk, Wk_b, n4_1m);
    cast_kernel<<<(n4_1m + 255) / 256, 256, 0, stream>>>(Wv, Wv_b, n4_1m);
    cast_kernel<<<(n4_1m + 255) / 256, 256, 0, stream>>>(Wo, Wo_b, n4_1m);
    cast_kernel<<<(n4_4m + 255) / 256, 256, 0, stream>>>(fc1_w, fc1_wb, n4_4m);
    cast_kernel<<<(n4_4m + 255) / 256, 256, 0, stream>>>(fc2_w, fc2_wb, n4_4m);

    // 1) LayerNorms (fp32 in, bf16 out)
    ln_kernel<<<2048, 256, 0, stream>>>(q_tokens, q_ln_w, q_ln_b, qn);
    ln_kernel<<<8192, 256, 0, stream>>>(kv_tokens, kv_ln_w, kv_ln_b, kvn);

    // 2) Projections (bf16 out)
    gemm_bt_kernel<0><<<dim3(8, 16), 256, 0, stream>>>(
        qn, Wq_b, 2048, 1024, 1024, nullptr, nullptr, nullptr, qbuf, nullptr);
    gemm_bt_kernel<0><<<dim3(8, 64), 256, 0, stream>>>(
        kvn, Wk_b, 8192, 1024, 1024, nullptr, nullptr, nullptr, kbuf, nullptr);
    gemm_bt_kernel<0><<<dim3(8, 64), 256, 0, stream>>>(
        kvn, Wv_b, 8192, 1024, 1024, nullptr, nullptr, nullptr, vbuf, nullptr);

    // 3) Per-head L2 norm (in place)
    l2norm_kernel<<<8192, 256, 0, stream>>>(qbuf, 32768);
    l2norm_kernel<<<32768, 256, 0, stream>>>(kbuf, 131072);

    // 4) V transpose for PV mfma (vbuf -> vtb; vtb overlays dead kvn)
    transpose_v_kernel<<<dim3(32, 16, 4), 256, 0, stream>>>(vbuf, vtb);

    // 5) Attention
    attn_kernel<<<dim3(8, 16, 4), 256, 0, stream>>>(qbuf, kbuf, vtb, ctx);

    // 6) Out-proj + residual: aout(fp32) = q_tokens + alpha*(ctx@Wo^T + bo)
    gemm_bt_kernel<1><<<dim3(8, 16), 256, 0, stream>>>(
        ctx, Wo_b, 2048, 1024, 1024, bo, q_tokens, alpha_attn, nullptr, aout);

    // 7) MLP LN (fp32 in, bf16 out)
    ln_kernel<<<2048, 256, 0, stream>>>(aout, mlp_ln_w, mlp_ln_b, hn);

    // 8) fc1 + exact GELU (bf16 out; h1 overlays dead vbuf)
    gemm_bt_kernel<2><<<dim3(32, 16), 256, 0, stream>>>(
        hn, fc1_wb, 2048, 4096, 1024, fc1_b, nullptr, nullptr, h1, nullptr);

    // 9) fc2 + residual -> d_out (fp32)
    gemm_bt_kernel<3><<<dim3(8, 16), 256, 0, stream>>>(
        h1, fc2_wb, 2048, 1024, 4096, fc2_b, aout, alpha_mlp, nullptr, (float*)d_out);
}

// Round 3
// 436.499 us; speedup vs baseline: 1.2870x; 1.2870x over previous
//
#include <hip/hip_runtime.h>

// ---------------------------------------------------------------------------
// CrossAttentionBlockPatched: B=4, Lq=512, Lkv=2048, DIM=1024, H=16, hd=64,
// MLP_HIDDEN=4096, TAU=2.0, EPS=1e-6. fp32 in/out, bf16 MFMA internally.
// ---------------------------------------------------------------------------

typedef __attribute__((ext_vector_type(8))) short short8_t;   // 8 x bf16
typedef __attribute__((ext_vector_type(4))) float f32x4_t;    // 4 x fp32

__device__ __forceinline__ float b2f(short s) {
    union { float f; unsigned u; } c;
    c.u = ((unsigned)(unsigned short)s) << 16;
    return c.f;
}
__device__ __forceinline__ short f2b(float f) {
    union { float f; unsigned u; } c;
    c.f = f;
    unsigned u = c.u;
    unsigned r = (u + 0x7FFFu + ((u >> 16) & 1u)) >> 16;
    return (short)r;
}

// async global -> LDS, 16 B per lane; lds base must be wave-uniform.
__device__ __forceinline__ void gload16(const void* g, void* l) {
    __builtin_amdgcn_global_load_lds(
        (const __attribute__((address_space(1))) void*)g,
        (__attribute__((address_space(3))) void*)l, 16, 0, 0);
}

// ---------------------------------------------------------------------------
// Fused fp32->bf16 cast of the 6 weight matrices (4x 1M elems + 2x 4M elems).
// ---------------------------------------------------------------------------
__global__ __launch_bounds__(256) void cast6_kernel(
    const float* __restrict__ w0, const float* __restrict__ w1,
    const float* __restrict__ w2, const float* __restrict__ w3,
    const float* __restrict__ w4, const float* __restrict__ w5,
    short* __restrict__ o0, short* __restrict__ o1,
    short* __restrict__ o2, short* __restrict__ o3,
    short* __restrict__ o4, short* __restrict__ o5)
{
    int f = blockIdx.x * 256 + threadIdx.x;   // float4 index, total 3145728
    const float* src; short* dst; int off;
    if (f < 1048576) {
        const int which = f >> 18; off = f & 262143;
        src = which == 0 ? w0 : which == 1 ? w1 : which == 2 ? w2 : w3;
        dst = which == 0 ? o0 : which == 1 ? o1 : which == 2 ? o2 : o3;
    } else {
        f -= 1048576;
        const int which = f >> 20; off = f & 1048575;
        src = which ? w5 : w4; dst = which ? o5 : o4;
    }
    const float4 v = ((const float4*)src)[off];
    short4 o;
    o.x = f2b(v.x); o.y = f2b(v.y); o.z = f2b(v.z); o.w = f2b(v.w);
    ((short4*)dst)[off] = o;
}

// ---------------------------------------------------------------------------
// LayerNorm: one block (256 thr) per 1024-elem row. fp32 in, bf16 out.
// ---------------------------------------------------------------------------
__global__ __launch_bounds__(256) void ln_kernel(
    const float* __restrict__ x, const float* __restrict__ w,
    const float* __restrict__ bia, short* __restrict__ y)
{
    const int row = blockIdx.x, tid = threadIdx.x;
    const float4 t = *(const float4*)(x + (size_t)row * 1024 + tid * 4);
    float v[4] = {t.x, t.y, t.z, t.w};
    float s = v[0] + v[1] + v[2] + v[3];
    float s2 = v[0]*v[0] + v[1]*v[1] + v[2]*v[2] + v[3]*v[3];
    #pragma unroll
    for (int off = 1; off < 64; off <<= 1) {
        s  += __shfl_xor(s, off);
        s2 += __shfl_xor(s2, off);
    }
    __shared__ float red[8];
    const int wave = tid >> 6, lane = tid & 63;
    if (lane == 0) { red[wave] = s; red[4 + wave] = s2; }
    __syncthreads();
    s  = red[0] + red[1] + red[2] + red[3];
    s2 = red[4] + red[5] + red[6] + red[7];
    const float mu  = s * (1.0f / 1024.0f);
    const float var = s2 * (1.0f / 1024.0f) - mu * mu;
    const float rstd = rsqrtf(var + 1e-6f);
    const float4 wv = *(const float4*)(w + tid * 4);
    const float4 bv = *(const float4*)(bia + tid * 4);
    short4 o;
    o.x = f2b((v[0] - mu) * rstd * wv.x + bv.x);
    o.y = f2b((v[1] - mu) * rstd * wv.y + bv.y);
    o.z = f2b((v[2] - mu) * rstd * wv.z + bv.z);
    o.w = f2b((v[3] - mu) * rstd * wv.w + bv.w);
    *(short4*)(y + (size_t)row * 1024 + tid * 4) = o;
}

// ---------------------------------------------------------------------------
// GEMM: C[M,N] = epilogue(A[M,K] @ W[N,K]^T), A/W bf16, BN=128, BK=32.
// BM=128: 4 waves as 2x2, wave = 64x64 (MI=4).  BM=64: wave = 32x64 (MI=2).
// Staging via global_load_lds w/ XOR-swizzled 16B column groups:
//   global colgroup g of row r is stored at LDS group g ^ s4(r),
//   s4(r) = (r&3)^((r>>2)&3)  -> fragment reads are 2-way conflicts (free).
// EPI: 0 plain bf16 | 1 outF = resF + alpha*(acc+bias) (fp32)
//      2 gelu_exact(acc+bias) bf16 | 4 l2norm(row,64-col head) bf16
//      5 l2norm + scatter to khd[b,h,kv,d] | 6 scatter to vhd[b,h,d,kv]
// ---------------------------------------------------------------------------
template <int EPI, int BM>
__global__ __launch_bounds__(256) void gemm_bt_kernel(
    const short* __restrict__ A, const short* __restrict__ W,
    int M, int N, int K,
    const float* __restrict__ bias,
    const float* __restrict__ resF,
    const float* __restrict__ alpha,
    short* __restrict__ out16,
    float* __restrict__ outF)
{
    constexpr int MI = (BM == 128) ? 4 : 2;
    __shared__ __attribute__((aligned(16))) short As[BM * 32];
    __shared__ __attribute__((aligned(16))) short Bs[128 * 32];
    const int bm = blockIdx.y * BM, bn = blockIdx.x * 128;
    const int tid = threadIdx.x;
    const int wave = tid >> 6, lane = tid & 63;
    const int wm = (wave >> 1) * (BM / 2), wn = (wave & 1) * 64;
    const int l15 = lane & 15, quad = lane >> 4;
    const int s4 = (l15 & 3) ^ ((l15 >> 2) & 3);   // swizzle for own frag rows
    const int fgrp = (quad ^ s4) * 8;              // frag read colgroup (shorts)

    f32x4_t acc[MI][4];
    #pragma unroll
    for (int mi = 0; mi < MI; ++mi)
        #pragma unroll
        for (int ni = 0; ni < 4; ++ni)
            acc[mi][ni] = (f32x4_t){0.f, 0.f, 0.f, 0.f};

    for (int k0 = 0; k0 < K; k0 += 32) {
        __syncthreads();
        // stage A tile (BM x 32 shorts = BM*64 B)
        #pragma unroll
        for (int c = 0; c < BM / 64; ++c) {
            const int o = c * 4096 + tid * 16;      // byte offset in tile
            const int row = o >> 6;
            const int gs = (o >> 4) & 3;
            const int g = gs ^ ((row & 3) ^ ((row >> 2) & 3));
            gload16(A + (size_t)(bm + row) * K + k0 + g * 8,
                    (char*)As + c * 4096 + wave * 1024);
        }
        // stage B tile (128 x 32 shorts)
        #pragma unroll
        for (int c = 0; c < 2; ++c) {
            const int o = c * 4096 + tid * 16;
            const int row = o >> 6;
            const int gs = (o >> 4) & 3;
            const int g = gs ^ ((row & 3) ^ ((row >> 2) & 3));
            gload16(W + (size_t)(bn + row) * K + k0 + g * 8,
                    (char*)Bs + c * 4096 + wave * 1024);
        }
        __syncthreads();   // compiler drains vmcnt(0) -> staged data visible
        short8_t af[MI], bf[4];
        #pragma unroll
        for (int mi = 0; mi < MI; ++mi)
            af[mi] = *(const short8_t*)&As[(wm + mi * 16 + l15) * 32 + fgrp];
        #pragma unroll
        for (int ni = 0; ni < 4; ++ni)
            bf[ni] = *(const short8_t*)&Bs[(wn + ni * 16 + l15) * 32 + fgrp];
        #pragma unroll
        for (int mi = 0; mi < MI; ++mi)
            #pragma unroll
            for (int ni = 0; ni < 4; ++ni)
                acc[mi][ni] = __builtin_amdgcn_mfma_f32_16x16x32_bf16(
                    af[mi], bf[ni], acc[mi][ni], 0, 0, 0);
    }

    // ---- epilogue ----
    if (EPI == 4 || EPI == 5) {   // per-row l2norm over this wave's 64 cols
        #pragma unroll
        for (int mi = 0; mi < MI; ++mi)
            #pragma unroll
            for (int r = 0; r < 4; ++r) {
                float s = 0.f;
                #pragma unroll
                for (int ni = 0; ni < 4; ++ni) {
                    const float x = acc[mi][ni][r];
                    s += x * x;
                }
                s += __shfl_xor(s, 1); s += __shfl_xor(s, 2);
                s += __shfl_xor(s, 4); s += __shfl_xor(s, 8);
                const float sc = 1.0f / fmaxf(sqrtf(s), 1e-6f);
                #pragma unroll
                for (int ni = 0; ni < 4; ++ni) acc[mi][ni][r] *= sc;
            }
    }

    const float a = (EPI == 1) ? alpha[0] : 0.f;
    #pragma unroll
    for (int mi = 0; mi < MI; ++mi) {
        #pragma unroll
        for (int ni = 0; ni < 4; ++ni) {
            const int n = bn + wn + ni * 16 + l15;
            const float bb = (EPI == 1 || EPI == 2) ? bias[n] : 0.f;
            #pragma unroll
            for (int r = 0; r < 4; ++r) {
                const int m = bm + wm + mi * 16 + quad * 4 + r;
                const float x = acc[mi][ni][r];
                if (EPI == 0 || EPI == 4) {
                    out16[(size_t)m * N + n] = f2b(x);
                } else if (EPI == 1) {
                    const size_t idx = (size_t)m * N + n;
                    outF[idx] = resF[idx] + a * (x + bb);
                } else if (EPI == 2) {
                    const float t = x + bb;
                    out16[(size_t)m * N + n] =
                        f2b(0.5f * t * (1.0f + erff(t * 0.70710678118f)));
                } else if (EPI == 5) {   // khd[b,h,kv,d]
                    out16[(size_t)(((m >> 11) * 16 + (n >> 6)) * 2048 +
                                   (m & 2047)) * 64 + (n & 63)] = f2b(x);
                } else if (EPI == 6) {   // vhd[b,h,d,kv]
                    out16[(size_t)(((m >> 11) * 16 + (n >> 6)) * 64 +
                                   (n & 63)) * 2048 + (m & 2047)] = f2b(x);
                }
            }
        }
    }
}

// ---------------------------------------------------------------------------
// Attention v2: block = (q-tile 64, head, batch); 4 waves x 16 Q rows.
// K/V tiles (64 kv x 64 d / 64 d x 64 kv) staged in LDS via global_load_lds,
// double-buffered, one barrier per tile. XOR-swizzle by row&7 on 16B groups.
// No running max needed: |q.k| <= 1 after l2norm -> p = exp(s/2) in [.6,1.65].
// ---------------------------------------------------------------------------
__global__ __launch_bounds__(256) void attn_kernel(
    const short* __restrict__ q, const short* __restrict__ khd,
    const short* __restrict__ vhd, short* __restrict__ ctx)
{
    const int qt = blockIdx.x;   // 0..7
    const int h  = blockIdx.y;   // 0..15
    const int b  = blockIdx.z;   // 0..3
    const int tid = threadIdx.x;
    const int wave = tid >> 6, lane = tid & 63;
    const int l15 = lane & 15, quad = lane >> 4;
    const int q0 = qt * 64 + wave * 16;

    __shared__ __attribute__((aligned(16))) short Ks[2][4096];
    __shared__ __attribute__((aligned(16))) short Vs[2][4096];
    __shared__ __attribute__((aligned(16))) short P[4][1152];   // 16 x 72

    // q fragments (registers, loaded once)
    const short* qbase = q + (size_t)(b * 512 + q0 + l15) * 1024 + h * 64 + quad * 8;
    const short8_t aq0 = *(const short8_t*)(qbase);
    const short8_t aq1 = *(const short8_t*)(qbase + 32);

    const short* kbase = khd + (size_t)(b * 16 + h) * 2048 * 64;  // [2048][64]
    const short* vbase = vhd + (size_t)(b * 16 + h) * 64 * 2048;  // [64][2048]

    const int swz = l15 & 7;
    const int g0 = (quad ^ swz) * 8;         // frag colgroup, k-half 0 (shorts)
    const int g1 = ((quad ^ swz) ^ 4) * 8;   // k-half 1

    auto stage = [&](int buf, int t) {
        #pragma unroll
        for (int c = 0; c < 2; ++c) {
            const int o = c * 4096 + tid * 16;   // byte offset in 8KB tile
            const int row = o >> 7;              // 64 rows x 128 B
            const int gs = (o >> 4) & 7;
            const int g = gs ^ (row & 7);
            gload16(kbase + (size_t)(t * 64 + row) * 64 + g * 8,
                    (char*)Ks[buf] + c * 4096 + wave * 1024);
            gload16(vbase + (size_t)row * 2048 + t * 64 + g * 8,
                    (char*)Vs[buf] + c * 4096 + wave * 1024);
        }
    };

    f32x4_t oacc[4];
    #pragma unroll
    for (int u = 0; u < 4; ++u) oacc[u] = (f32x4_t){0.f, 0.f, 0.f, 0.f};
    float l[4] = {0.f, 0.f, 0.f, 0.f};

    stage(0, 0);
    for (int t = 0; t < 32; ++t) {
        const int buf = t & 1;
        __syncthreads();   // stage(t) complete; prev compute done with buf^1
        if (t + 1 < 32) stage(buf ^ 1, t + 1);

        // S = Q K^T  (16 q x 64 kv)
        f32x4_t s[4];
        #pragma unroll
        for (int ss = 0; ss < 4; ++ss) {
            const int R = ss * 16 + l15;
            const short8_t bk0 = *(const short8_t*)&Ks[buf][R * 64 + g0];
            const short8_t bk1 = *(const short8_t*)&Ks[buf][R * 64 + g1];
            f32x4_t a = (f32x4_t){0.f, 0.f, 0.f, 0.f};
            a = __builtin_amdgcn_mfma_f32_16x16x32_bf16(aq0, bk0, a, 0, 0, 0);
            a = __builtin_amdgcn_mfma_f32_16x16x32_bf16(aq1, bk1, a, 0, 0, 0);
            s[ss] = a;
        }
        // P = exp(S/2), row sums
        float rs[4] = {0.f, 0.f, 0.f, 0.f};
        #pragma unroll
        for (int ss = 0; ss < 4; ++ss)
            #pragma unroll
            for (int r = 0; r < 4; ++r) {
                const float p = __expf(s[ss][r] * 0.5f);
                s[ss][r] = p;
                rs[r] += p;
            }
        #pragma unroll
        for (int r = 0; r < 4; ++r) {
            float v = rs[r];
            v += __shfl_xor(v, 1); v += __shfl_xor(v, 2);
            v += __shfl_xor(v, 4); v += __shfl_xor(v, 8);
            l[r] += v;
        }
        // P: C-layout -> LDS (per-wave region) -> A-layout fragments
        #pragma unroll
        for (int ss = 0; ss < 4; ++ss)
            #pragma unroll
            for (int r = 0; r < 4; ++r)
                P[wave][(quad * 4 + r) * 72 + ss * 16 + l15] = f2b(s[ss][r]);
        const short8_t ap0 = *(const short8_t*)&P[wave][l15 * 72 + quad * 8];
        const short8_t ap1 = *(const short8_t*)&P[wave][l15 * 72 + 32 + quad * 8];
        // O += P V   (16 q x 64 d)
        #pragma unroll
        for (int u = 0; u < 4; ++u) {
            const int R = u * 16 + l15;
            const short8_t bv0 = *(const short8_t*)&Vs[buf][R * 64 + g0];
            const short8_t bv1 = *(const short8_t*)&Vs[buf][R * 64 + g1];
            oacc[u] = __builtin_amdgcn_mfma_f32_16x16x32_bf16(ap0, bv0, oacc[u], 0, 0, 0);
            oacc[u] = __builtin_amdgcn_mfma_f32_16x16x32_bf16(ap1, bv1, oacc[u], 0, 0, 0);
        }
    }
    #pragma unroll
    for (int u = 0; u < 4; ++u)
        #pragma unroll
        for (int r = 0; r < 4; ++r) {
            const float val = oacc[u][r] / l[r];
            ctx[(size_t)(b * 512 + q0 + quad * 4 + r) * 1024 + h * 64 + u * 16 + l15] =
                f2b(val);
        }
}

// ---------------------------------------------------------------------------
extern "C" void kernel_launch(void* const* d_in, const int* in_sizes, int n_in,
                              void* d_out, int out_size, void* d_ws, size_t ws_size,
                              hipStream_t stream)
{
    const float* q_tokens  = (const float*)d_in[0];
    const float* kv_tokens = (const float*)d_in[1];
    const float* q_ln_w    = (const float*)d_in[2];
    const float* q_ln_b    = (const float*)d_in[3];
    const float* kv_ln_w   = (const float*)d_in[4];
    const float* kv_ln_b   = (const float*)d_in[5];
    const float* mlp_ln_w  = (const float*)d_in[6];
    const float* mlp_ln_b  = (const float*)d_in[7];
    const float* Wq        = (const float*)d_in[8];
    const float* Wk        = (const float*)d_in[9];
    const float* Wv        = (const float*)d_in[10];
    const float* Wo        = (const float*)d_in[11];
    const float* bo        = (const float*)d_in[12];
    const float* fc1_w     = (const float*)d_in[13];
    const float* fc1_b     = (const float*)d_in[14];
    const float* fc2_w     = (const float*)d_in[15];
    const float* fc2_b     = (const float*)d_in[16];
    const float* alpha_attn = (const float*)d_in[17];
    const float* alpha_mlp  = (const float*)d_in[18];

    char* ws = (char*)d_ws;
    const size_t MB = (size_t)1 << 20;
    short* khd   = (short*)(ws);             // 16 MB [4,16,2048,64] bf16
    short* vhd   = (short*)(ws + 16 * MB);   // 16 MB [4,16,64,2048]
    short* kvn   = (short*)(ws + 32 * MB);   // 16 MB [8192,1024]; dead after v-proj
    short* h1    = (short*)(ws + 32 * MB);   //       overlays kvn: [2048,4096]
    short* qn    = (short*)(ws + 48 * MB);   //  4 MB [2048,1024]
    short* qbuf  = (short*)(ws + 52 * MB);   //  4 MB [2048,1024] (l2-normed q)
    short* ctx   = (short*)(ws + 56 * MB);   //  4 MB [2048,1024]
    float* aout  = (float*)(ws + 60 * MB);   //  8 MB [2048,1024] fp32
    short* hn    = (short*)(ws + 68 * MB);   //  4 MB [2048,1024]
    short* Wq_b  = (short*)(ws + 72 * MB);   //  2 MB each
    short* Wk_b  = (short*)(ws + 74 * MB);
    short* Wv_b  = (short*)(ws + 76 * MB);
    short* Wo_b  = (short*)(ws + 78 * MB);
    short* fc1_wb = (short*)(ws + 80 * MB);  //  8 MB
    short* fc2_wb = (short*)(ws + 88 * MB);  //  8 MB

    // 0) cast all weights fp32 -> bf16 (one kernel)
    cast6_kernel<<<12288, 256, 0, stream>>>(Wq, Wk, Wv, Wo, fc1_w, fc2_w,
                                            Wq_b, Wk_b, Wv_b, Wo_b, fc1_wb, fc2_wb);

    // 1) LayerNorms (fp32 in, bf16 out)
    ln_kernel<<<2048, 256, 0, stream>>>(q_tokens, q_ln_w, q_ln_b, qn);
    ln_kernel<<<8192, 256, 0, stream>>>(kv_tokens, kv_ln_w, kv_ln_b, kvn);

    // 2) Projections with fused l2norm / layout scatter
    gemm_bt_kernel<4, 64><<<dim3(8, 32), 256, 0, stream>>>(
        qn, Wq_b, 2048, 1024, 1024, nullptr, nullptr, nullptr, qbuf, nullptr);
    gemm_bt_kernel<5, 128><<<dim3(8, 64), 256, 0, stream>>>(
        kvn, Wk_b, 8192, 1024, 1024, nullptr, nullptr, nullptr, khd, nullptr);
    gemm_bt_kernel<6, 128><<<dim3(8, 64), 256, 0, stream>>>(
        kvn, Wv_b, 8192, 1024, 1024, nullptr, nullptr, nullptr, vhd, nullptr);

    // 3) Attention
    attn_kernel<<<dim3(8, 16, 4), 256, 0, stream>>>(qbuf, khd, vhd, ctx);

    // 4) Out-proj + residual: aout = q_tokens + alpha*(ctx@Wo^T + bo)
    gemm_bt_kernel<1, 64><<<dim3(8, 32), 256, 0, stream>>>(
        ctx, Wo_b, 2048, 1024, 1024, bo, q_tokens, alpha_attn, nullptr, aout);

    // 5) MLP LN
    ln_kernel<<<2048, 256, 0, stream>>>(aout, mlp_ln_w, mlp_ln_b, hn);

    // 6) fc1 + exact GELU
    gemm_bt_kernel<2, 128><<<dim3(32, 16), 256, 0, stream>>>(
        hn, fc1_wb, 2048, 4096, 1024, fc1_b, nullptr, nullptr, h1, nullptr);

    // 7) fc2 + residual -> d_out (fp32)
    gemm_bt_kernel<1, 64><<<dim3(8, 32), 256, 0, stream>>>(
        h1, fc2_wb, 2048, 1024, 4096, fc2_b, aout, alpha_mlp, nullptr, (float*)d_out);
}

// Round 4
// 410.052 us; speedup vs baseline: 1.3700x; 1.0645x over previous
//
#include <hip/hip_runtime.h>

// ---------------------------------------------------------------------------
// CrossAttentionBlockPatched: B=4, Lq=512, Lkv=2048, DIM=1024, H=16, hd=64,
// MLP_HIDDEN=4096, TAU=2.0, EPS=1e-6. fp32 in/out, bf16 MFMA internally.
// ---------------------------------------------------------------------------

typedef __attribute__((ext_vector_type(8))) short short8_t;   // 8 x bf16
typedef __attribute__((ext_vector_type(4))) float f32x4_t;    // 4 x fp32

__device__ __forceinline__ float b2f(short s) {
    union { float f; unsigned u; } c;
    c.u = ((unsigned)(unsigned short)s) << 16;
    return c.f;
}
__device__ __forceinline__ short f2b(float f) {
    union { float f; unsigned u; } c;
    c.f = f;
    unsigned u = c.u;
    unsigned r = (u + 0x7FFFu + ((u >> 16) & 1u)) >> 16;
    return (short)r;
}

// async global -> LDS, 16 B per lane; lds base must be wave-uniform.
__device__ __forceinline__ void gload16(const void* g, void* l) {
    __builtin_amdgcn_global_load_lds(
        (const __attribute__((address_space(1))) void*)g,
        (__attribute__((address_space(3))) void*)l, 16, 0, 0);
}

// ---------------------------------------------------------------------------
// Fused fp32->bf16 cast of the 6 weight matrices. Wk/Wv go to a stacked
// [2048,1024] buffer (Wk rows 0..1023, Wv rows 1024..2047).
// ---------------------------------------------------------------------------
__global__ __launch_bounds__(256) void cast6_kernel(
    const float* __restrict__ w0, const float* __restrict__ w1,
    const float* __restrict__ w2, const float* __restrict__ w3,
    const float* __restrict__ w4, const float* __restrict__ w5,
    short* __restrict__ o0, short* __restrict__ o1,
    short* __restrict__ o2, short* __restrict__ o3,
    short* __restrict__ o4, short* __restrict__ o5)
{
    int f = blockIdx.x * 256 + threadIdx.x;   // float4 index, total 3145728
    const float* src; short* dst; int off;
    if (f < 1048576) {
        const int which = f >> 18; off = f & 262143;
        src = which == 0 ? w0 : which == 1 ? w1 : which == 2 ? w2 : w3;
        dst = which == 0 ? o0 : which == 1 ? o1 : which == 2 ? o2 : o3;
    } else {
        f -= 1048576;
        const int which = f >> 20; off = f & 1048575;
        src = which ? w5 : w4; dst = which ? o5 : o4;
    }
    const float4 v = ((const float4*)src)[off];
    short4 o;
    o.x = f2b(v.x); o.y = f2b(v.y); o.z = f2b(v.z); o.w = f2b(v.w);
    ((short4*)dst)[off] = o;
}

// ---------------------------------------------------------------------------
// LayerNorm: one block (256 thr) per 1024-elem row. fp32 in, bf16 out.
// ---------------------------------------------------------------------------
__global__ __launch_bounds__(256) void ln_kernel(
    const float* __restrict__ x, const float* __restrict__ w,
    const float* __restrict__ bia, short* __restrict__ y)
{
    const int row = blockIdx.x, tid = threadIdx.x;
    const float4 t = *(const float4*)(x + (size_t)row * 1024 + tid * 4);
    float v[4] = {t.x, t.y, t.z, t.w};
    float s = v[0] + v[1] + v[2] + v[3];
    float s2 = v[0]*v[0] + v[1]*v[1] + v[2]*v[2] + v[3]*v[3];
    #pragma unroll
    for (int off = 1; off < 64; off <<= 1) {
        s  += __shfl_xor(s, off);
        s2 += __shfl_xor(s2, off);
    }
    __shared__ float red[8];
    const int wave = tid >> 6, lane = tid & 63;
    if (lane == 0) { red[wave] = s; red[4 + wave] = s2; }
    __syncthreads();
    s  = red[0] + red[1] + red[2] + red[3];
    s2 = red[4] + red[5] + red[6] + red[7];
    const float mu  = s * (1.0f / 1024.0f);
    const float var = s2 * (1.0f / 1024.0f) - mu * mu;
    const float rstd = rsqrtf(var + 1e-6f);
    const float4 wv = *(const float4*)(w + tid * 4);
    const float4 bv = *(const float4*)(bia + tid * 4);
    short4 o;
    o.x = f2b((v[0] - mu) * rstd * wv.x + bv.x);
    o.y = f2b((v[1] - mu) * rstd * wv.y + bv.y);
    o.z = f2b((v[2] - mu) * rstd * wv.z + bv.z);
    o.w = f2b((v[3] - mu) * rstd * wv.w + bv.w);
    *(short4*)(y + (size_t)row * 1024 + tid * 4) = o;
}

// ---------------------------------------------------------------------------
// GEMM: C[M,N] = epilogue(A[M,K] @ W[N,K]^T), bf16 in, BN=128, BK=32,
// double-buffered LDS (one barrier per K-step, prefetch in flight during
// compute). Ks = K elements this block accumulates (split-K slice), Kst = row
// stride of A (full K). blockIdx.z = split-K slice index.
// BM=128: 4 waves as 2x2, wave = 64x64 (MI=4).  BM=64: wave = 32x64 (MI=2).
// XOR-swizzled 16B column groups: colgroup g of row r stored at g ^ s4(r),
// s4(r)=(r&3)^((r>>2)&3) -> fragment reads are 2-way conflicts (free).
// EPI: 1 outF = resF + alpha*(acc+bias) (fp32)
//      2 gelu_exact(acc+bias) bf16 (fc1)
//      4 l2norm(row, 64-col head) bf16 (q-proj)
//      7 fp32 partial to outF + z*M*N (split-K)
//      8 fused KV: n<1024 -> l2norm + scatter khd[b,h,kv,d] (out16);
//                  n>=1024 -> scatter vhd[b,h,d,kv] ((short*)outF)
// ---------------------------------------------------------------------------
template <int EPI, int BM>
__global__ __launch_bounds__(256) void gemm_bt_kernel(
    const short* __restrict__ A, const short* __restrict__ W,
    int M, int N, int Ks, int Kst,
    const float* __restrict__ bias,
    const float* __restrict__ resF,
    const float* __restrict__ alpha,
    short* __restrict__ out16,
    float* __restrict__ outF)
{
    constexpr int MI = (BM == 128) ? 4 : 2;
    __shared__ __attribute__((aligned(16))) short As[2][BM * 32];
    __shared__ __attribute__((aligned(16))) short Bs[2][128 * 32];
    const int bm = blockIdx.y * BM, bn = blockIdx.x * 128;
    const size_t kbase = (size_t)blockIdx.z * Ks;
    const int tid = threadIdx.x;
    const int wave = tid >> 6, lane = tid & 63;
    const int wm = (wave >> 1) * (BM / 2), wn = (wave & 1) * 64;
    const int l15 = lane & 15, quad = lane >> 4;
    const int s4 = (l15 & 3) ^ ((l15 >> 2) & 3);
    const int fgrp = (quad ^ s4) * 8;   // frag read colgroup (shorts)

    f32x4_t acc[MI][4];
    #pragma unroll
    for (int mi = 0; mi < MI; ++mi)
        #pragma unroll
        for (int ni = 0; ni < 4; ++ni)
            acc[mi][ni] = (f32x4_t){0.f, 0.f, 0.f, 0.f};

    auto stage = [&](int buf, int k0) {
        #pragma unroll
        for (int c = 0; c < BM / 64; ++c) {
            const int o = c * 4096 + tid * 16;
            const int row = o >> 6;
            const int g = ((o >> 4) & 3) ^ ((row & 3) ^ ((row >> 2) & 3));
            gload16(A + (size_t)(bm + row) * Kst + kbase + k0 + g * 8,
                    (char*)As[buf] + c * 4096 + wave * 1024);
        }
        #pragma unroll
        for (int c = 0; c < 2; ++c) {
            const int o = c * 4096 + tid * 16;
            const int row = o >> 6;
            const int g = ((o >> 4) & 3) ^ ((row & 3) ^ ((row >> 2) & 3));
            gload16(W + (size_t)(bn + row) * Kst + kbase + k0 + g * 8,
                    (char*)Bs[buf] + c * 4096 + wave * 1024);
        }
    };

    const int nIter = Ks >> 5;
    stage(0, 0);
    for (int it = 0; it < nIter; ++it) {
        const int buf = it & 1;
        __syncthreads();   // drains stage(it); prev compute done with buf^1
        if (it + 1 < nIter) stage(buf ^ 1, (it + 1) * 32);
        short8_t af[MI], bf[4];
        #pragma unroll
        for (int mi = 0; mi < MI; ++mi)
            af[mi] = *(const short8_t*)&As[buf][(wm + mi * 16 + l15) * 32 + fgrp];
        #pragma unroll
        for (int ni = 0; ni < 4; ++ni)
            bf[ni] = *(const short8_t*)&Bs[buf][(wn + ni * 16 + l15) * 32 + fgrp];
        #pragma unroll
        for (int mi = 0; mi < MI; ++mi)
            #pragma unroll
            for (int ni = 0; ni < 4; ++ni)
                acc[mi][ni] = __builtin_amdgcn_mfma_f32_16x16x32_bf16(
                    af[mi], bf[ni], acc[mi][ni], 0, 0, 0);
    }

    // ---- epilogue ----
    if (EPI == 4 || (EPI == 8 && (bn + wn) < 1024)) {   // l2norm over 64-col head
        #pragma unroll
        for (int mi = 0; mi < MI; ++mi)
            #pragma unroll
            for (int r = 0; r < 4; ++r) {
                float s = 0.f;
                #pragma unroll
                for (int ni = 0; ni < 4; ++ni) {
                    const float x = acc[mi][ni][r];
                    s += x * x;
                }
                s += __shfl_xor(s, 1); s += __shfl_xor(s, 2);
                s += __shfl_xor(s, 4); s += __shfl_xor(s, 8);
                const float sc = 1.0f / fmaxf(sqrtf(s), 1e-6f);
                #pragma unroll
                for (int ni = 0; ni < 4; ++ni) acc[mi][ni][r] *= sc;
            }
    }

    const float a = (EPI == 1) ? alpha[0] : 0.f;
    #pragma unroll
    for (int mi = 0; mi < MI; ++mi) {
        #pragma unroll
        for (int ni = 0; ni < 4; ++ni) {
            const int n = bn + wn + ni * 16 + l15;
            const float bb = (EPI == 1 || EPI == 2) ? bias[n] : 0.f;
            #pragma unroll
            for (int r = 0; r < 4; ++r) {
                const int m = bm + wm + mi * 16 + quad * 4 + r;
                const float x = acc[mi][ni][r];
                if (EPI == 4) {
                    out16[(size_t)m * N + n] = f2b(x);
                } else if (EPI == 1) {
                    const size_t idx = (size_t)m * N + n;
                    outF[idx] = resF[idx] + a * (x + bb);
                } else if (EPI == 2) {
                    const float t = x + bb;
                    out16[(size_t)m * N + n] =
                        f2b(0.5f * t * (1.0f + erff(t * 0.70710678118f)));
                } else if (EPI == 7) {
                    outF[(size_t)blockIdx.z * M * N + (size_t)m * N + n] = x;
                } else if (EPI == 8) {
                    if (n < 1024) {       // khd[b,h,kv,d]
                        out16[(size_t)(((m >> 11) * 16 + (n >> 6)) * 2048 +
                                       (m & 2047)) * 64 + (n & 63)] = f2b(x);
                    } else {              // vhd[b,h,d,kv]
                        const int nn = n - 1024;
                        ((short*)outF)[(size_t)(((m >> 11) * 16 + (nn >> 6)) * 64 +
                                       (nn & 63)) * 2048 + (m & 2047)] = f2b(x);
                    }
                }
            }
        }
    }
}

// ---------------------------------------------------------------------------
// Split-K reduce for fc2: out = resF + alpha*(p0+p1+p2+p3 + bias). N=1024.
// ---------------------------------------------------------------------------
__global__ __launch_bounds__(256) void reduce4_kernel(
    const float* __restrict__ parts, const float* __restrict__ resF,
    const float* __restrict__ bias, const float* __restrict__ alpha,
    float* __restrict__ out)
{
    const int i = blockIdx.x * 256 + threadIdx.x;   // float4 index over 2048x1024
    const size_t MN4 = (size_t)2048 * 1024 / 4;
    const float a = alpha[0];
    const float4 b4 = ((const float4*)bias)[i & 255];
    float4 s = ((const float4*)parts)[i];
    const float4 p1 = ((const float4*)parts)[MN4 + i];
    const float4 p2 = ((const float4*)parts)[2 * MN4 + i];
    const float4 p3 = ((const float4*)parts)[3 * MN4 + i];
    const float4 rv = ((const float4*)resF)[i];
    float4 o;
    o.x = rv.x + a * (s.x + p1.x + p2.x + p3.x + b4.x);
    o.y = rv.y + a * (s.y + p1.y + p2.y + p3.y + b4.y);
    o.z = rv.z + a * (s.z + p1.z + p2.z + p3.z + b4.z);
    o.w = rv.w + a * (s.w + p1.w + p2.w + p3.w + b4.w);
    ((float4*)out)[i] = o;
}

// ---------------------------------------------------------------------------
// Attention: block = (q-tile 64, head, batch); 4 waves x 16 Q rows.
// K/V tiles staged via global_load_lds, double-buffered, 1 barrier/tile.
// No running max needed: |q.k| <= 1 after l2norm.
// ---------------------------------------------------------------------------
__global__ __launch_bounds__(256) void attn_kernel(
    const short* __restrict__ q, const short* __restrict__ khd,
    const short* __restrict__ vhd, short* __restrict__ ctx)
{
    const int qt = blockIdx.x;   // 0..7
    const int h  = blockIdx.y;   // 0..15
    const int b  = blockIdx.z;   // 0..3
    const int tid = threadIdx.x;
    const int wave = tid >> 6, lane = tid & 63;
    const int l15 = lane & 15, quad = lane >> 4;
    const int q0 = qt * 64 + wave * 16;

    __shared__ __attribute__((aligned(16))) short Ks[2][4096];
    __shared__ __attribute__((aligned(16))) short Vs[2][4096];
    __shared__ __attribute__((aligned(16))) short P[4][1152];   // 16 x 72

    const short* qbase = q + (size_t)(b * 512 + q0 + l15) * 1024 + h * 64 + quad * 8;
    const short8_t aq0 = *(const short8_t*)(qbase);
    const short8_t aq1 = *(const short8_t*)(qbase + 32);

    const short* kbase = khd + (size_t)(b * 16 + h) * 2048 * 64;  // [2048][64]
    const short* vbase = vhd + (size_t)(b * 16 + h) * 64 * 2048;  // [64][2048]

    const int swz = l15 & 7;
    const int g0 = (quad ^ swz) * 8;
    const int g1 = ((quad ^ swz) ^ 4) * 8;

    auto stage = [&](int buf, int t) {
        #pragma unroll
        for (int c = 0; c < 2; ++c) {
            const int o = c * 4096 + tid * 16;
            const int row = o >> 7;              // 64 rows x 128 B
            const int g = ((o >> 4) & 7) ^ (row & 7);
            gload16(kbase + (size_t)(t * 64 + row) * 64 + g * 8,
                    (char*)Ks[buf] + c * 4096 + wave * 1024);
            gload16(vbase + (size_t)row * 2048 + t * 64 + g * 8,
                    (char*)Vs[buf] + c * 4096 + wave * 1024);
        }
    };

    f32x4_t oacc[4];
    #pragma unroll
    for (int u = 0; u < 4; ++u) oacc[u] = (f32x4_t){0.f, 0.f, 0.f, 0.f};
    float l[4] = {0.f, 0.f, 0.f, 0.f};

    stage(0, 0);
    for (int t = 0; t < 32; ++t) {
        const int buf = t & 1;
        __syncthreads();
        if (t + 1 < 32) stage(buf ^ 1, t + 1);

        f32x4_t s[4];
        #pragma unroll
        for (int ss = 0; ss < 4; ++ss) {
            const int R = ss * 16 + l15;
            const short8_t bk0 = *(const short8_t*)&Ks[buf][R * 64 + g0];
            const short8_t bk1 = *(const short8_t*)&Ks[buf][R * 64 + g1];
            f32x4_t a = (f32x4_t){0.f, 0.f, 0.f, 0.f};
            a = __builtin_amdgcn_mfma_f32_16x16x32_bf16(aq0, bk0, a, 0, 0, 0);
            a = __builtin_amdgcn_mfma_f32_16x16x32_bf16(aq1, bk1, a, 0, 0, 0);
            s[ss] = a;
        }
        float rs[4] = {0.f, 0.f, 0.f, 0.f};
        #pragma unroll
        for (int ss = 0; ss < 4; ++ss)
            #pragma unroll
            for (int r = 0; r < 4; ++r) {
                const float p = __expf(s[ss][r] * 0.5f);
                s[ss][r] = p;
                rs[r] += p;
            }
        #pragma unroll
        for (int r = 0; r < 4; ++r) {
            float v = rs[r];
            v += __shfl_xor(v, 1); v += __shfl_xor(v, 2);
            v += __shfl_xor(v, 4); v += __shfl_xor(v, 8);
            l[r] += v;
        }
        #pragma unroll
        for (int ss = 0; ss < 4; ++ss)
            #pragma unroll
            for (int r = 0; r < 4; ++r)
                P[wave][(quad * 4 + r) * 72 + ss * 16 + l15] = f2b(s[ss][r]);
        const short8_t ap0 = *(const short8_t*)&P[wave][l15 * 72 + quad * 8];
        const short8_t ap1 = *(const short8_t*)&P[wave][l15 * 72 + 32 + quad * 8];
        #pragma unroll
        for (int u = 0; u < 4; ++u) {
            const int R = u * 16 + l15;
            const short8_t bv0 = *(const short8_t*)&Vs[buf][R * 64 + g0];
            const short8_t bv1 = *(const short8_t*)&Vs[buf][R * 64 + g1];
            oacc[u] = __builtin_amdgcn_mfma_f32_16x16x32_bf16(ap0, bv0, oacc[u], 0, 0, 0);
            oacc[u] = __builtin_amdgcn_mfma_f32_16x16x32_bf16(ap1, bv1, oacc[u], 0, 0, 0);
        }
    }
    #pragma unroll
    for (int u = 0; u < 4; ++u)
        #pragma unroll
        for (int r = 0; r < 4; ++r) {
            const float val = oacc[u][r] / l[r];
            ctx[(size_t)(b * 512 + q0 + quad * 4 + r) * 1024 + h * 64 + u * 16 + l15] =
                f2b(val);
        }
}

// ---------------------------------------------------------------------------
extern "C" void kernel_launch(void* const* d_in, const int* in_sizes, int n_in,
                              void* d_out, int out_size, void* d_ws, size_t ws_size,
                              hipStream_t stream)
{
    const float* q_tokens  = (const float*)d_in[0];
    const float* kv_tokens = (const float*)d_in[1];
    const float* q_ln_w    = (const float*)d_in[2];
    const float* q_ln_b    = (const float*)d_in[3];
    const float* kv_ln_w   = (const float*)d_in[4];
    const float* kv_ln_b   = (const float*)d_in[5];
    const float* mlp_ln_w  = (const float*)d_in[6];
    const float* mlp_ln_b  = (const float*)d_in[7];
    const float* Wq        = (const float*)d_in[8];
    const float* Wk        = (const float*)d_in[9];
    const float* Wv        = (const float*)d_in[10];
    const float* Wo        = (const float*)d_in[11];
    const float* bo        = (const float*)d_in[12];
    const float* fc1_w     = (const float*)d_in[13];
    const float* fc1_b     = (const float*)d_in[14];
    const float* fc2_w     = (const float*)d_in[15];
    const float* fc2_b     = (const float*)d_in[16];
    const float* alpha_attn = (const float*)d_in[17];
    const float* alpha_mlp  = (const float*)d_in[18];

    char* ws = (char*)d_ws;
    const size_t MB = (size_t)1 << 20;
    short* khd   = (short*)(ws);             // 16 MB [4,16,2048,64]; dead after attn
    short* vhd   = (short*)(ws + 16 * MB);   // 16 MB [4,16,64,2048]; dead after attn
    float* parts = (float*)(ws);             // 32 MB fc2 split-K partials (overlays khd+vhd)
    short* kvn   = (short*)(ws + 32 * MB);   // 16 MB [8192,1024]; dead after kv-proj
    short* h1    = (short*)(ws + 32 * MB);   //       overlays kvn: [2048,4096]
    short* qn    = (short*)(ws + 48 * MB);   //  4 MB [2048,1024]
    short* qbuf  = (short*)(ws + 52 * MB);   //  4 MB [2048,1024] (l2-normed q)
    short* ctx   = (short*)(ws + 56 * MB);   //  4 MB [2048,1024]
    float* aout  = (float*)(ws + 60 * MB);   //  8 MB [2048,1024] fp32
    short* hn    = (short*)(ws + 68 * MB);   //  4 MB [2048,1024]
    short* Wq_b  = (short*)(ws + 72 * MB);   //  2 MB
    short* Wkv_b = (short*)(ws + 74 * MB);   //  4 MB stacked [2048,1024]
    short* Wo_b  = (short*)(ws + 78 * MB);   //  2 MB
    short* fc1_wb = (short*)(ws + 80 * MB);  //  8 MB
    short* fc2_wb = (short*)(ws + 88 * MB);  //  8 MB

    // 0) cast all weights fp32 -> bf16 (Wk/Wv stacked)
    cast6_kernel<<<12288, 256, 0, stream>>>(Wq, Wk, Wv, Wo, fc1_w, fc2_w,
                                            Wq_b, Wkv_b, Wkv_b + 1048576, Wo_b,
                                            fc1_wb, fc2_wb);

    // 1) LayerNorms (fp32 in, bf16 out)
    ln_kernel<<<2048, 256, 0, stream>>>(q_tokens, q_ln_w, q_ln_b, qn);
    ln_kernel<<<8192, 256, 0, stream>>>(kv_tokens, kv_ln_w, kv_ln_b, kvn);

    // 2) q-proj (+l2norm) and fused kv-proj (+l2norm/scatter)
    gemm_bt_kernel<4, 64><<<dim3(8, 32), 256, 0, stream>>>(
        qn, Wq_b, 2048, 1024, 1024, 1024, nullptr, nullptr, nullptr, qbuf, nullptr);
    gemm_bt_kernel<8, 128><<<dim3(16, 64), 256, 0, stream>>>(
        kvn, Wkv_b, 8192, 2048, 1024, 1024, nullptr, nullptr, nullptr,
        khd, (float*)vhd);

    // 3) Attention
    attn_kernel<<<dim3(8, 16, 4), 256, 0, stream>>>(qbuf, khd, vhd, ctx);

    // 4) Out-proj + residual: aout = q_tokens + alpha*(ctx@Wo^T + bo)
    gemm_bt_kernel<1, 64><<<dim3(8, 32), 256, 0, stream>>>(
        ctx, Wo_b, 2048, 1024, 1024, 1024, bo, q_tokens, alpha_attn, nullptr, aout);

    // 5) MLP LN
    ln_kernel<<<2048, 256, 0, stream>>>(aout, mlp_ln_w, mlp_ln_b, hn);

    // 6) fc1 + exact GELU
    gemm_bt_kernel<2, 128><<<dim3(32, 16), 256, 0, stream>>>(
        hn, fc1_wb, 2048, 4096, 1024, 1024, fc1_b, nullptr, nullptr, h1, nullptr);

    // 7) fc2 split-K x4 -> fp32 partials, then reduce + residual -> d_out
    gemm_bt_kernel<7, 64><<<dim3(8, 32, 4), 256, 0, stream>>>(
        h1, fc2_wb, 2048, 1024, 1024, 4096, nullptr, nullptr, nullptr,
        nullptr, parts);
    reduce4_kernel<<<2048, 256, 0, stream>>>(parts, aout, fc2_b, alpha_mlp,
                                             (float*)d_out);
}

// Round 5
// 390.813 us; speedup vs baseline: 1.4375x; 1.0492x over previous
//
#include <hip/hip_runtime.h>

// ---------------------------------------------------------------------------
// CrossAttentionBlockPatched: B=4, Lq=512, Lkv=2048, DIM=1024, H=16, hd=64,
// MLP_HIDDEN=4096, TAU=2.0, EPS=1e-6. fp32 in/out, bf16 MFMA internally.
// ---------------------------------------------------------------------------

typedef __attribute__((ext_vector_type(8))) short short8_t;   // 8 x bf16
typedef __attribute__((ext_vector_type(4))) float f32x4_t;    // 4 x fp32

__device__ __forceinline__ float b2f(short s) {
    union { float f; unsigned u; } c;
    c.u = ((unsigned)(unsigned short)s) << 16;
    return c.f;
}
__device__ __forceinline__ short f2b(float f) {
    union { float f; unsigned u; } c;
    c.f = f;
    unsigned u = c.u;
    unsigned r = (u + 0x7FFFu + ((u >> 16) & 1u)) >> 16;
    return (short)r;
}

// async global -> LDS, 16 B per lane; lds base must be wave-uniform.
__device__ __forceinline__ void gload16(const void* g, void* l) {
    __builtin_amdgcn_global_load_lds(
        (const __attribute__((address_space(1))) void*)g,
        (__attribute__((address_space(3))) void*)l, 16, 0, 0);
}

// ---------------------------------------------------------------------------
// Fused fp32->bf16 cast of the 6 weight matrices. Wk/Wv go to a stacked
// [2048,1024] buffer (Wk rows 0..1023, Wv rows 1024..2047).
// ---------------------------------------------------------------------------
__global__ __launch_bounds__(256) void cast6_kernel(
    const float* __restrict__ w0, const float* __restrict__ w1,
    const float* __restrict__ w2, const float* __restrict__ w3,
    const float* __restrict__ w4, const float* __restrict__ w5,
    short* __restrict__ o0, short* __restrict__ o1,
    short* __restrict__ o2, short* __restrict__ o3,
    short* __restrict__ o4, short* __restrict__ o5)
{
    int f = blockIdx.x * 256 + threadIdx.x;   // float4 index, total 3145728
    const float* src; short* dst; int off;
    if (f < 1048576) {
        const int which = f >> 18; off = f & 262143;
        src = which == 0 ? w0 : which == 1 ? w1 : which == 2 ? w2 : w3;
        dst = which == 0 ? o0 : which == 1 ? o1 : which == 2 ? o2 : o3;
    } else {
        f -= 1048576;
        const int which = f >> 20; off = f & 1048575;
        src = which ? w5 : w4; dst = which ? o5 : o4;
    }
    const float4 v = ((const float4*)src)[off];
    short4 o;
    o.x = f2b(v.x); o.y = f2b(v.y); o.z = f2b(v.z); o.w = f2b(v.w);
    ((short4*)dst)[off] = o;
}

// ---------------------------------------------------------------------------
// LayerNorm: one block (256 thr) per 1024-elem row. fp32 in, bf16 out.
// ---------------------------------------------------------------------------
__global__ __launch_bounds__(256) void ln_kernel(
    const float* __restrict__ x, const float* __restrict__ w,
    const float* __restrict__ bia, short* __restrict__ y)
{
    const int row = blockIdx.x, tid = threadIdx.x;
    const float4 t = *(const float4*)(x + (size_t)row * 1024 + tid * 4);
    float v[4] = {t.x, t.y, t.z, t.w};
    float s = v[0] + v[1] + v[2] + v[3];
    float s2 = v[0]*v[0] + v[1]*v[1] + v[2]*v[2] + v[3]*v[3];
    #pragma unroll
    for (int off = 1; off < 64; off <<= 1) {
        s  += __shfl_xor(s, off);
        s2 += __shfl_xor(s2, off);
    }
    __shared__ float red[8];
    const int wave = tid >> 6, lane = tid & 63;
    if (lane == 0) { red[wave] = s; red[4 + wave] = s2; }
    __syncthreads();
    s  = red[0] + red[1] + red[2] + red[3];
    s2 = red[4] + red[5] + red[6] + red[7];
    const float mu  = s * (1.0f / 1024.0f);
    const float var = s2 * (1.0f / 1024.0f) - mu * mu;
    const float rstd = rsqrtf(var + 1e-6f);
    const float4 wv = *(const float4*)(w + tid * 4);
    const float4 bv = *(const float4*)(bia + tid * 4);
    short4 o;
    o.x = f2b((v[0] - mu) * rstd * wv.x + bv.x);
    o.y = f2b((v[1] - mu) * rstd * wv.y + bv.y);
    o.z = f2b((v[2] - mu) * rstd * wv.z + bv.z);
    o.w = f2b((v[3] - mu) * rstd * wv.w + bv.w);
    *(short4*)(y + (size_t)row * 1024 + tid * 4) = o;
}

// ---------------------------------------------------------------------------
// GEMM: C[M,N] = epilogue(A[M,K] @ W[N,K]^T), bf16 in, BN=128, BK=64,
// single-buffered LDS, 2 barriers per K-step (m97 structure). LDS rows are
// 128 B (64 shorts) with 3-bit XOR swizzle: element (row,k) lives at group
// (k>>3)^(row&7) -> ds_read_b128 fragment reads are exactly the 8-phase
// minimum (conflict-free), unlike 64 B rows which alias every 2 rows.
// Ks = K this block accumulates (split-K slice), Kst = A/W row stride.
// BM=128: 4 waves as 2x2, wave = 64x64 (MI=4).  BM=64: wave = 32x64 (MI=2).
// EPI: 1 outF = resF + alpha*(acc+bias) (fp32)
//      2 gelu_exact(acc+bias) bf16 (fc1)
//      4 l2norm(row, 64-col head) bf16 (q-proj)
//      7 fp32 partial to outF + z*M*N (split-K)
//      8 fused KV: n<1024 -> l2norm + scatter khd[b,h,kv,d] (out16);
//                  n>=1024 -> scatter vhd[b,h,d,kv] ((short*)outF)
// ---------------------------------------------------------------------------
template <int EPI, int BM>
__global__ __launch_bounds__(256) void gemm_bt_kernel(
    const short* __restrict__ A, const short* __restrict__ W,
    int M, int N, int Ks, int Kst,
    const float* __restrict__ bias,
    const float* __restrict__ resF,
    const float* __restrict__ alpha,
    short* __restrict__ out16,
    float* __restrict__ outF)
{
    constexpr int MI = (BM == 128) ? 4 : 2;
    __shared__ __attribute__((aligned(16))) short As[BM * 64];
    __shared__ __attribute__((aligned(16))) short Bs[128 * 64];
    const int bm = blockIdx.y * BM, bn = blockIdx.x * 128;
    const size_t kbase = (size_t)blockIdx.z * Ks;
    const int tid = threadIdx.x;
    const int wave = tid >> 6, lane = tid & 63;
    const int wm = (wave >> 1) * (BM / 2), wn = (wave & 1) * 64;
    const int l15 = lane & 15, quad = lane >> 4;
    const int l7 = l15 & 7;   // == row&7 of this lane's fragment rows

    f32x4_t acc[MI][4];
    #pragma unroll
    for (int mi = 0; mi < MI; ++mi)
        #pragma unroll
        for (int ni = 0; ni < 4; ++ni)
            acc[mi][ni] = (f32x4_t){0.f, 0.f, 0.f, 0.f};

    auto stage = [&](int k0) {
        #pragma unroll
        for (int c = 0; c < BM / 32; ++c) {       // A: BM*128 B
            const int o = c * 4096 + tid * 16;
            const int row = o >> 7;
            const int g = ((o >> 4) & 7) ^ (row & 7);
            gload16(A + (size_t)(bm + row) * Kst + kbase + k0 + g * 8,
                    (char*)As + c * 4096 + wave * 1024);
        }
        #pragma unroll
        for (int c = 0; c < 4; ++c) {             // B: 128*128 B
            const int o = c * 4096 + tid * 16;
            const int row = o >> 7;
            const int g = ((o >> 4) & 7) ^ (row & 7);
            gload16(W + (size_t)(bn + row) * Kst + kbase + k0 + g * 8,
                    (char*)Bs + c * 4096 + wave * 1024);
        }
    };

    const int nIter = Ks >> 6;
    for (int it = 0; it < nIter; ++it) {
        __syncthreads();            // prev compute done reading LDS
        stage(it * 64);
        __syncthreads();            // drains vmcnt(0): staged data visible
        #pragma unroll
        for (int h = 0; h < 2; ++h) {
            const int fg = (((h << 2) | quad) ^ l7) * 8;
            short8_t af[MI], bf[4];
            #pragma unroll
            for (int mi = 0; mi < MI; ++mi)
                af[mi] = *(const short8_t*)&As[(wm + mi * 16 + l15) * 64 + fg];
            #pragma unroll
            for (int ni = 0; ni < 4; ++ni)
                bf[ni] = *(const short8_t*)&Bs[(wn + ni * 16 + l15) * 64 + fg];
            #pragma unroll
            for (int mi = 0; mi < MI; ++mi)
                #pragma unroll
                for (int ni = 0; ni < 4; ++ni)
                    acc[mi][ni] = __builtin_amdgcn_mfma_f32_16x16x32_bf16(
                        af[mi], bf[ni], acc[mi][ni], 0, 0, 0);
        }
    }

    // ---- epilogue ----
    if (EPI == 4 || (EPI == 8 && (bn + wn) < 1024)) {   // l2norm over 64-col head
        #pragma unroll
        for (int mi = 0; mi < MI; ++mi)
            #pragma unroll
            for (int r = 0; r < 4; ++r) {
                float s = 0.f;
                #pragma unroll
                for (int ni = 0; ni < 4; ++ni) {
                    const float x = acc[mi][ni][r];
                    s += x * x;
                }
                s += __shfl_xor(s, 1); s += __shfl_xor(s, 2);
                s += __shfl_xor(s, 4); s += __shfl_xor(s, 8);
                const float sc = 1.0f / fmaxf(sqrtf(s), 1e-6f);
                #pragma unroll
                for (int ni = 0; ni < 4; ++ni) acc[mi][ni][r] *= sc;
            }
    }

    const float a = (EPI == 1) ? alpha[0] : 0.f;
    #pragma unroll
    for (int mi = 0; mi < MI; ++mi) {
        #pragma unroll
        for (int ni = 0; ni < 4; ++ni) {
            const int n = bn + wn + ni * 16 + l15;
            const float bb = (EPI == 1 || EPI == 2) ? bias[n] : 0.f;
            #pragma unroll
            for (int r = 0; r < 4; ++r) {
                const int m = bm + wm + mi * 16 + (quad << 2) + r;
                const float x = acc[mi][ni][r];
                if (EPI == 4) {
                    out16[(size_t)m * N + n] = f2b(x);
                } else if (EPI == 1) {
                    const size_t idx = (size_t)m * N + n;
                    outF[idx] = resF[idx] + a * (x + bb);
                } else if (EPI == 2) {
                    const float t = x + bb;
                    out16[(size_t)m * N + n] =
                        f2b(0.5f * t * (1.0f + erff(t * 0.70710678118f)));
                } else if (EPI == 7) {
                    outF[(size_t)blockIdx.z * M * N + (size_t)m * N + n] = x;
                } else if (EPI == 8) {
                    if (n < 1024) {       // khd[b,h,kv,d]
                        out16[(size_t)(((m >> 11) * 16 + (n >> 6)) * 2048 +
                                       (m & 2047)) * 64 + (n & 63)] = f2b(x);
                    } else {              // vhd[b,h,d,kv]
                        const int nn = n - 1024;
                        ((short*)outF)[(size_t)(((m >> 11) * 16 + (nn >> 6)) * 64 +
                                       (nn & 63)) * 2048 + (m & 2047)] = f2b(x);
                    }
                }
            }
        }
    }
}

// ---------------------------------------------------------------------------
// Split-K reduce for fc2: out = resF + alpha*(p0+p1+p2+p3 + bias). N=1024.
// ---------------------------------------------------------------------------
__global__ __launch_bounds__(256) void reduce4_kernel(
    const float* __restrict__ parts, const float* __restrict__ resF,
    const float* __restrict__ bias, const float* __restrict__ alpha,
    float* __restrict__ out)
{
    const int i = blockIdx.x * 256 + threadIdx.x;   // float4 index over 2048x1024
    const size_t MN4 = (size_t)2048 * 1024 / 4;
    const float a = alpha[0];
    const float4 b4 = ((const float4*)bias)[i & 255];
    float4 s = ((const float4*)parts)[i];
    const float4 p1 = ((const float4*)parts)[MN4 + i];
    const float4 p2 = ((const float4*)parts)[2 * MN4 + i];
    const float4 p3 = ((const float4*)parts)[3 * MN4 + i];
    const float4 rv = ((const float4*)resF)[i];
    float4 o;
    o.x = rv.x + a * (s.x + p1.x + p2.x + p3.x + b4.x);
    o.y = rv.y + a * (s.y + p1.y + p2.y + p3.y + b4.y);
    o.z = rv.z + a * (s.z + p1.z + p2.z + p3.z + b4.z);
    o.w = rv.w + a * (s.w + p1.w + p2.w + p3.w + b4.w);
    ((float4*)out)[i] = o;
}

// ---------------------------------------------------------------------------
// Attention: block = (q-tile 64, head, batch); 4 waves x 16 Q rows.
// K/V tiles staged via global_load_lds, double-buffered, 1 barrier/tile.
// 128 B LDS rows + 3-bit row XOR (conflict-free b128 reads).
// No running max needed: |q.k| <= 1 after l2norm.
// ---------------------------------------------------------------------------
__global__ __launch_bounds__(256) void attn_kernel(
    const short* __restrict__ q, const short* __restrict__ khd,
    const short* __restrict__ vhd, short* __restrict__ ctx)
{
    const int qt = blockIdx.x;   // 0..7
    const int h  = blockIdx.y;   // 0..15
    const int b  = blockIdx.z;   // 0..3
    const int tid = threadIdx.x;
    const int wave = tid >> 6, lane = tid & 63;
    const int l15 = lane & 15, quad = lane >> 4;
    const int q0 = qt * 64 + wave * 16;

    __shared__ __attribute__((aligned(16))) short Ks[2][4096];
    __shared__ __attribute__((aligned(16))) short Vs[2][4096];
    __shared__ __attribute__((aligned(16))) short P[4][1152];   // 16 x 72

    const short* qbase = q + (size_t)(b * 512 + q0 + l15) * 1024 + h * 64 + quad * 8;
    const short8_t aq0 = *(const short8_t*)(qbase);
    const short8_t aq1 = *(const short8_t*)(qbase + 32);

    const short* kbase = khd + (size_t)(b * 16 + h) * 2048 * 64;  // [2048][64]
    const short* vbase = vhd + (size_t)(b * 16 + h) * 64 * 2048;  // [64][2048]

    const int swz = l15 & 7;
    const int g0 = (quad ^ swz) * 8;
    const int g1 = ((quad ^ swz) ^ 4) * 8;

    auto stage = [&](int buf, int t) {
        #pragma unroll
        for (int c = 0; c < 2; ++c) {
            const int o = c * 4096 + tid * 16;
            const int row = o >> 7;              // 64 rows x 128 B
            const int g = ((o >> 4) & 7) ^ (row & 7);
            gload16(kbase + (size_t)(t * 64 + row) * 64 + g * 8,
                    (char*)Ks[buf] + c * 4096 + wave * 1024);
            gload16(vbase + (size_t)row * 2048 + t * 64 + g * 8,
                    (char*)Vs[buf] + c * 4096 + wave * 1024);
        }
    };

    f32x4_t oacc[4];
    #pragma unroll
    for (int u = 0; u < 4; ++u) oacc[u] = (f32x4_t){0.f, 0.f, 0.f, 0.f};
    float l[4] = {0.f, 0.f, 0.f, 0.f};

    stage(0, 0);
    for (int t = 0; t < 32; ++t) {
        const int buf = t & 1;
        __syncthreads();
        if (t + 1 < 32) stage(buf ^ 1, t + 1);

        f32x4_t s[4];
        #pragma unroll
        for (int ss = 0; ss < 4; ++ss) {
            const int R = ss * 16 + l15;
            const short8_t bk0 = *(const short8_t*)&Ks[buf][R * 64 + g0];
            const short8_t bk1 = *(const short8_t*)&Ks[buf][R * 64 + g1];
            f32x4_t a = (f32x4_t){0.f, 0.f, 0.f, 0.f};
            a = __builtin_amdgcn_mfma_f32_16x16x32_bf16(aq0, bk0, a, 0, 0, 0);
            a = __builtin_amdgcn_mfma_f32_16x16x32_bf16(aq1, bk1, a, 0, 0, 0);
            s[ss] = a;
        }
        float rs[4] = {0.f, 0.f, 0.f, 0.f};
        #pragma unroll
        for (int ss = 0; ss < 4; ++ss)
            #pragma unroll
            for (int r = 0; r < 4; ++r) {
                const float p = __expf(s[ss][r] * 0.5f);
                s[ss][r] = p;
                rs[r] += p;
            }
        #pragma unroll
        for (int r = 0; r < 4; ++r) {
            float v = rs[r];
            v += __shfl_xor(v, 1); v += __shfl_xor(v, 2);
            v += __shfl_xor(v, 4); v += __shfl_xor(v, 8);
            l[r] += v;
        }
        #pragma unroll
        for (int ss = 0; ss < 4; ++ss)
            #pragma unroll
            for (int r = 0; r < 4; ++r)
                P[wave][(quad * 4 + r) * 72 + ss * 16 + l15] = f2b(s[ss][r]);
        const short8_t ap0 = *(const short8_t*)&P[wave][l15 * 72 + quad * 8];
        const short8_t ap1 = *(const short8_t*)&P[wave][l15 * 72 + 32 + quad * 8];
        #pragma unroll
        for (int u = 0; u < 4; ++u) {
            const int R = u * 16 + l15;
            const short8_t bv0 = *(const short8_t*)&Vs[buf][R * 64 + g0];
            const short8_t bv1 = *(const short8_t*)&Vs[buf][R * 64 + g1];
            oacc[u] = __builtin_amdgcn_mfma_f32_16x16x32_bf16(ap0, bv0, oacc[u], 0, 0, 0);
            oacc[u] = __builtin_amdgcn_mfma_f32_16x16x32_bf16(ap1, bv1, oacc[u], 0, 0, 0);
        }
    }
    #pragma unroll
    for (int u = 0; u < 4; ++u)
        #pragma unroll
        for (int r = 0; r < 4; ++r) {
            const float val = oacc[u][r] / l[r];
            ctx[(size_t)(b * 512 + q0 + quad * 4 + r) * 1024 + h * 64 + u * 16 + l15] =
                f2b(val);
        }
}

// ---------------------------------------------------------------------------
extern "C" void kernel_launch(void* const* d_in, const int* in_sizes, int n_in,
                              void* d_out, int out_size, void* d_ws, size_t ws_size,
                              hipStream_t stream)
{
    const float* q_tokens  = (const float*)d_in[0];
    const float* kv_tokens = (const float*)d_in[1];
    const float* q_ln_w    = (const float*)d_in[2];
    const float* q_ln_b    = (const float*)d_in[3];
    const float* kv_ln_w   = (const float*)d_in[4];
    const float* kv_ln_b   = (const float*)d_in[5];
    const float* mlp_ln_w  = (const float*)d_in[6];
    const float* mlp_ln_b  = (const float*)d_in[7];
    const float* Wq        = (const float*)d_in[8];
    const float* Wk        = (const float*)d_in[9];
    const float* Wv        = (const float*)d_in[10];
    const float* Wo        = (const float*)d_in[11];
    const float* bo        = (const float*)d_in[12];
    const float* fc1_w     = (const float*)d_in[13];
    const float* fc1_b     = (const float*)d_in[14];
    const float* fc2_w     = (const float*)d_in[15];
    const float* fc2_b     = (const float*)d_in[16];
    const float* alpha_attn = (const float*)d_in[17];
    const float* alpha_mlp  = (const float*)d_in[18];

    char* ws = (char*)d_ws;
    const size_t MB = (size_t)1 << 20;
    short* khd   = (short*)(ws);             // 16 MB [4,16,2048,64]; dead after attn
    short* vhd   = (short*)(ws + 16 * MB);   // 16 MB [4,16,64,2048]; dead after attn
    float* parts = (float*)(ws);             // 32 MB fc2 split-K partials (overlays khd+vhd)
    short* kvn   = (short*)(ws + 32 * MB);   // 16 MB [8192,1024]; dead after kv-proj
    short* h1    = (short*)(ws + 32 * MB);   //       overlays kvn: [2048,4096]
    short* qn    = (short*)(ws + 48 * MB);   //  4 MB [2048,1024]
    short* qbuf  = (short*)(ws + 52 * MB);   //  4 MB [2048,1024] (l2-normed q)
    short* ctx   = (short*)(ws + 56 * MB);   //  4 MB [2048,1024]
    float* aout  = (float*)(ws + 60 * MB);   //  8 MB [2048,1024] fp32
    short* hn    = (short*)(ws + 68 * MB);   //  4 MB [2048,1024]
    short* Wq_b  = (short*)(ws + 72 * MB);   //  2 MB
    short* Wkv_b = (short*)(ws + 74 * MB);   //  4 MB stacked [2048,1024]
    short* Wo_b  = (short*)(ws + 78 * MB);   //  2 MB
    short* fc1_wb = (short*)(ws + 80 * MB);  //  8 MB
    short* fc2_wb = (short*)(ws + 88 * MB);  //  8 MB

    // 0) cast all weights fp32 -> bf16 (Wk/Wv stacked)
    cast6_kernel<<<12288, 256, 0, stream>>>(Wq, Wk, Wv, Wo, fc1_w, fc2_w,
                                            Wq_b, Wkv_b, Wkv_b + 1048576, Wo_b,
                                            fc1_wb, fc2_wb);

    // 1) LayerNorms (fp32 in, bf16 out)
    ln_kernel<<<2048, 256, 0, stream>>>(q_tokens, q_ln_w, q_ln_b, qn);
    ln_kernel<<<8192, 256, 0, stream>>>(kv_tokens, kv_ln_w, kv_ln_b, kvn);

    // 2) q-proj (+l2norm) and fused kv-proj (+l2norm/scatter)
    gemm_bt_kernel<4, 64><<<dim3(8, 32), 256, 0, stream>>>(
        qn, Wq_b, 2048, 1024, 1024, 1024, nullptr, nullptr, nullptr, qbuf, nullptr);
    gemm_bt_kernel<8, 128><<<dim3(16, 64), 256, 0, stream>>>(
        kvn, Wkv_b, 8192, 2048, 1024, 1024, nullptr, nullptr, nullptr,
        khd, (float*)vhd);

    // 3) Attention
    attn_kernel<<<dim3(8, 16, 4), 256, 0, stream>>>(qbuf, khd, vhd, ctx);

    // 4) Out-proj + residual: aout = q_tokens + alpha*(ctx@Wo^T + bo)
    gemm_bt_kernel<1, 64><<<dim3(8, 32), 256, 0, stream>>>(
        ctx, Wo_b, 2048, 1024, 1024, 1024, bo, q_tokens, alpha_attn, nullptr, aout);

    // 5) MLP LN
    ln_kernel<<<2048, 256, 0, stream>>>(aout, mlp_ln_w, mlp_ln_b, hn);

    // 6) fc1 + exact GELU
    gemm_bt_kernel<2, 128><<<dim3(32, 16), 256, 0, stream>>>(
        hn, fc1_wb, 2048, 4096, 1024, 1024, fc1_b, nullptr, nullptr, h1, nullptr);

    // 7) fc2 split-K x4 -> fp32 partials, then reduce + residual -> d_out
    gemm_bt_kernel<7, 64><<<dim3(8, 32, 4), 256, 0, stream>>>(
        h1, fc2_wb, 2048, 1024, 1024, 4096, nullptr, nullptr, nullptr,
        nullptr, parts);
    reduce4_kernel<<<2048, 256, 0, stream>>>(parts, aout, fc2_b, alpha_mlp,
                                             (float*)d_out);
}